// Round 20
// baseline (120.892 us; speedup 1.0000x reference)
//
#include <hip/hip_runtime.h>
#include <hip/hip_bf16.h>
#include <cstdint>
#include <cstddef>

typedef __hip_bfloat16 bf16;
typedef __attribute__((ext_vector_type(8))) short bf16x8;
typedef __attribute__((ext_vector_type(4))) float f32x4;
typedef __attribute__((ext_vector_type(16))) float f32x16;

#define AS1C(p) ((const __attribute__((address_space(1))) void*)(p))
#define AS3(p)  ((__attribute__((address_space(3))) void*)(p))

constexpr int B_ = 2, S_ = 2048, E_ = 1024, H_ = 16, D_ = 64;
constexpr int M_ = B_ * S_;                      // 4096
constexpr float QSCALE_ = 0.125f * 1.44269504088896340736f;  // 1/sqrt(64) * log2(e)

__device__ __forceinline__ void gload_lds16(const bf16* g, bf16* l) {
  __builtin_amdgcn_global_load_lds(AS1C(g), AS3(l), 16, 0, 0);
}

__device__ __forceinline__ void cast4(const float* __restrict__ in, bf16* __restrict__ out, int i) {
  float4 v = reinterpret_cast<const float4*>(in)[i];
  union { bf16 b[4]; short4 s; } u;
  u.b[0] = __float2bfloat16(v.x);
  u.b[1] = __float2bfloat16(v.y);
  u.b[2] = __float2bfloat16(v.z);
  u.b[3] = __float2bfloat16(v.w);
  reinterpret_cast<short4*>(out)[i] = u.s;
}

// ---------------- fused prep: casts + rope tables + bias concat ----------------
__global__ void prep_kernel(const float* __restrict__ x,
                            const float* __restrict__ Wq, const float* __restrict__ Wk,
                            const float* __restrict__ Wv, const float* __restrict__ Wo,
                            const float* __restrict__ bq, const float* __restrict__ bk,
                            const float* __restrict__ bv,
                            bf16* __restrict__ xb, bf16* __restrict__ Wqkvb,
                            bf16* __restrict__ Wob, float* __restrict__ bqkv,
                            float* __restrict__ sintab, float* __restrict__ costab) {
  const int b = blockIdx.x, t = threadIdx.x;
  if (b < 4096) {
    cast4(x, xb, b * 256 + t);
  } else if (b < 5120) {
    cast4(Wo, Wob, (b - 4096) * 256 + t);
  } else if (b < 8192) {
    const int i = (b - 5120) * 256 + t;
    const int which = i >> 18;
    const int j = i & ((1 << 18) - 1);
    const float* src = which == 0 ? Wq : (which == 1 ? Wk : Wv);
    cast4(src, Wqkvb + (size_t)which * E_ * E_, j);
  } else if (b < 8448) {
    const int idx = (b - 8192) * 256 + t;
    const int s = idx >> 5, i = idx & 31;
    float inv = powf(10000.0f, -(float)i / 32.0f);
    float ang = (float)s * inv;
    sintab[idx] = sinf(ang);
    costab[idx] = cosf(ang);
  } else {
    for (int j = t; j < 768; j += 256) {
      const int which = j >> 8, jj = j & 255;
      const float* src = which == 0 ? bq : (which == 1 ? bk : bv);
      reinterpret_cast<float4*>(bqkv)[j] = reinterpret_cast<const float4*>(src)[jj];
    }
  }
}

// ---------------- QKV GEMM: 128x128, chunk-XOR swizzle, 2-phase double-buffered K-loop ----------------
__global__ __launch_bounds__(256)
void gemm_qkv(const bf16* __restrict__ A, const bf16* __restrict__ W,
              const float* __restrict__ bias,
              bf16* __restrict__ Qo, bf16* __restrict__ Ko, bf16* __restrict__ Vo,
              const float* __restrict__ sintab, const float* __restrict__ costab)
{
  constexpr int K = 1024, BK = 32;
  __shared__ __align__(16) bf16 smem[17408];
  const int tid = threadIdx.x;
  const int lane = tid & 63, wid = tid >> 6;
  const int g = lane >> 4, r16 = lane & 15;
  const int wr = wid >> 1, wc = wid & 1;
  const int swzr = (r16 >> 1) & 3;

  const int nwg = gridDim.x * gridDim.y;
  const int flat = blockIdx.y * gridDim.x + blockIdx.x;
  const int cpx = nwg >> 3;
  const int f2 = (flat & 7) * cpx + (flat >> 3);
  const int m0 = (f2 / gridDim.x) * 128, n0 = (f2 % gridDim.x) * 128;

  const f32x4 fz = {0.f, 0.f, 0.f, 0.f};
  f32x4 acc[4][4];
#pragma unroll
  for (int mi = 0; mi < 4; ++mi)
#pragma unroll
    for (int ni = 0; ni < 4; ++ni) acc[mi][ni] = fz;

  const bf16* Abase = A + (size_t)m0 * K;
  const bf16* Wbase = W + (size_t)n0 * K;
  const int c0 = tid, c1 = 256 + tid;
  const int r0c = c0 >> 2, cc0 = c0 & 3, sw0 = (r0c >> 1) & 3;
  const int r1c = c1 >> 2, cc1 = c1 & 3, sw1 = (r1c >> 1) & 3;

  auto stage = [&](int k0, int buf) {
    bf16* As = smem + buf * 4096;
    bf16* Bs = smem + 8192 + buf * 4096;
    gload_lds16(Abase + (size_t)r0c * K + k0 + ((cc0 ^ sw0) * 8), As + c0 * 8);
    gload_lds16(Abase + (size_t)r1c * K + k0 + ((cc1 ^ sw1) * 8), As + c1 * 8);
    gload_lds16(Wbase + (size_t)r0c * K + k0 + ((cc0 ^ sw0) * 8), Bs + c0 * 8);
    gload_lds16(Wbase + (size_t)r1c * K + k0 + ((cc1 ^ sw1) * 8), Bs + c1 * 8);
  };

  stage(0, 0);
  __syncthreads();
  int buf = 0;

  for (int k0 = 0; k0 < K; k0 += BK) {
    if (k0 + BK < K) stage(k0 + BK, buf ^ 1);

    const bf16* As = smem + buf * 4096;
    const bf16* Bs = smem + 8192 + buf * 4096;
    bf16x8 af[4], bfr[4];
#pragma unroll
    for (int mi = 0; mi < 4; ++mi)
      af[mi] = *reinterpret_cast<const bf16x8*>(
          As + (wr * 64 + mi * 16 + r16) * BK + 8 * (g ^ swzr));
#pragma unroll
    for (int ni = 0; ni < 4; ++ni)
      bfr[ni] = *reinterpret_cast<const bf16x8*>(
          Bs + (wc * 64 + ni * 16 + r16) * BK + 8 * (g ^ swzr));
    __builtin_amdgcn_s_setprio(1);
#pragma unroll
    for (int mi = 0; mi < 4; ++mi)
#pragma unroll
      for (int ni = 0; ni < 4; ++ni)
        acc[mi][ni] = __builtin_amdgcn_mfma_f32_16x16x32_bf16(af[mi], bfr[ni], acc[mi][ni], 0, 0, 0);
    __builtin_amdgcn_s_setprio(0);

    __syncthreads();
    buf ^= 1;
  }

  const int b = m0 >> 11;
  if (n0 >= 2048) {
#pragma unroll
    for (int mi = 0; mi < 4; ++mi) {
#pragma unroll
      for (int ni = 0; ni < 4; ++ni) {
        const int n_local = wc * 64 + ni * 16 + r16;
        const float bv = bias[n0 + n_local];
        const int m_base = wr * 64 + mi * 16 + g * 4;
        union { bf16 b4[4]; short4 s4; } u;
#pragma unroll
        for (int r = 0; r < 4; ++r) u.b4[r] = __float2bfloat16(acc[mi][ni][r] + bv);
        *reinterpret_cast<short4*>(&smem[n_local * 136 + m_base]) = u.s4;
      }
    }
    __syncthreads();
    const int srow0 = m0 & (S_ - 1);
#pragma unroll
    for (int i = 0; i < 8; ++i) {
      const int c = i * 256 + tid;
      const int row = c >> 4, cc = c & 15;
      const bf16x8 v = *reinterpret_cast<const bf16x8*>(&smem[row * 136 + cc * 8]);
      const int n = n0 + row;
      const int h = (n >> 6) & 15, d = n & 63;
      *reinterpret_cast<bf16x8*>(&Vo[((size_t)(b * H_ + h) * D_ + d) * S_ + srow0 + cc * 8]) = v;
    }
  } else {
#pragma unroll
    for (int mi = 0; mi < 4; ++mi) {
#pragma unroll
      for (int ni = 0; ni < 4; ++ni) {
        const int gn = n0 + wc * 64 + ni * 16 + r16;
        const float bv = bias[gn];
#pragma unroll
        for (int r = 0; r < 4; ++r) {
          const int gm = m0 + wr * 64 + mi * 16 + g * 4 + r;
          float val = acc[mi][ni][r] + bv;
          const int d = gn & 63;
          const int srow = gm & (S_ - 1);
          const float cs = costab[srow * 32 + (d >> 1)];
          const float sn = sintab[srow * 32 + (d >> 1)];
          const float pv = __shfl_xor(val, 1);
          val = (d & 1) ? (val * cs + pv * sn) : (val * cs - pv * sn);
          const int h = (gn >> 6) & 15;
          const size_t bh = (size_t)(b * H_ + h);
          if (gn < 1024) {
            Qo[(bh * S_ + srow) * D_ + d] = __float2bfloat16(val * QSCALE_);
          } else {
            Ko[(bh * S_ + srow) * D_ + d] = __float2bfloat16(val);
          }
        }
      }
    }
  }
}

// ---------------- O-projection GEMM: BM=64 x BN=128, swizzle + 2-phase dbuf ----------------
__global__ __launch_bounds__(256)
void gemm_o(const bf16* __restrict__ A, const bf16* __restrict__ W,
            const float* __restrict__ bias, float* __restrict__ outF)
{
  constexpr int K = 1024, BK = 32;
  __shared__ __align__(16) bf16 As[2][64 * BK];
  __shared__ __align__(16) bf16 Bs[2][128 * BK];
  const int tid = threadIdx.x;
  const int lane = tid & 63;
  const int wc = tid >> 6;
  const int g = lane >> 4, r16 = lane & 15;
  const int swzr = (r16 >> 1) & 3;

  const int flat = blockIdx.x;                    // 512
  const int f2 = (flat & 7) * 64 + (flat >> 3);
  const int m0 = (f2 >> 3) * 64, n0 = (f2 & 7) * 128;

  const f32x4 fz = {0.f, 0.f, 0.f, 0.f};
  f32x4 acc[4][2];
#pragma unroll
  for (int mi = 0; mi < 4; ++mi)
#pragma unroll
    for (int ni = 0; ni < 2; ++ni) acc[mi][ni] = fz;

  const bf16* Abase = A + (size_t)m0 * K;
  const bf16* Wbase = W + (size_t)n0 * K;
  const int c0 = tid, c1 = 256 + tid;
  const int r0c = c0 >> 2, cc0 = c0 & 3, sw0 = (r0c >> 1) & 3;
  const int r1c = c1 >> 2, cc1 = c1 & 3, sw1 = (r1c >> 1) & 3;

  auto stage = [&](int k0, int buf) {
    gload_lds16(Abase + (size_t)r0c * K + k0 + ((cc0 ^ sw0) * 8), As[buf] + c0 * 8);
    gload_lds16(Wbase + (size_t)r0c * K + k0 + ((cc0 ^ sw0) * 8), Bs[buf] + c0 * 8);
    gload_lds16(Wbase + (size_t)r1c * K + k0 + ((cc1 ^ sw1) * 8), Bs[buf] + c1 * 8);
  };

  stage(0, 0);
  __syncthreads();
  int buf = 0;

  for (int k0 = 0; k0 < K; k0 += BK) {
    if (k0 + BK < K) stage(k0 + BK, buf ^ 1);

    bf16x8 af[4], bfr[2];
#pragma unroll
    for (int mi = 0; mi < 4; ++mi)
      af[mi] = *reinterpret_cast<const bf16x8*>(
          As[buf] + (mi * 16 + r16) * BK + 8 * (g ^ swzr));
#pragma unroll
    for (int ni = 0; ni < 2; ++ni)
      bfr[ni] = *reinterpret_cast<const bf16x8*>(
          Bs[buf] + (wc * 32 + ni * 16 + r16) * BK + 8 * (g ^ swzr));
    __builtin_amdgcn_s_setprio(1);
#pragma unroll
    for (int mi = 0; mi < 4; ++mi)
#pragma unroll
      for (int ni = 0; ni < 2; ++ni)
        acc[mi][ni] = __builtin_amdgcn_mfma_f32_16x16x32_bf16(af[mi], bfr[ni], acc[mi][ni], 0, 0, 0);
    __builtin_amdgcn_s_setprio(0);

    __syncthreads();
    buf ^= 1;
  }

#pragma unroll
  for (int mi = 0; mi < 4; ++mi)
#pragma unroll
    for (int ni = 0; ni < 2; ++ni) {
      const int gn = n0 + wc * 32 + ni * 16 + r16;
      const float bv = bias[gn];
#pragma unroll
      for (int r = 0; r < 4; ++r) {
        const int gm = m0 + mi * 16 + g * 4 + r;
        outF[(size_t)gm * 1024 + gn] = acc[mi][ni][r] + bv;
      }
    }
}

// ---------------- causal flash attention v13: complementary CU pairing ----------------
// Block i and i+256 land on the same CU (XCD=i&7, slot=(i>>3)&31): map first 256 blocks to
// qblks 15..8 and second 256 to qblks 0..7 so every CU totals exactly 17 supersteps.
__global__ __launch_bounds__(512)
void attn_kernel(const bf16* __restrict__ Q, const bf16* __restrict__ Kg,
                 const bf16* __restrict__ Vtg, bf16* __restrict__ Og)
{
  __shared__ __align__(16) bf16 Ks[2][2][64 * 64];   // [dbuf][tile-in-pair][k][d]
  __shared__ __align__(16) bf16 Vs[2][2][64 * 64];   // [dbuf][tile-in-pair][d][k]
  const int flat = blockIdx.x;
  const int bh = flat & 31;
  const int qblk = (flat < 256) ? (15 - (flat >> 5)) : ((flat >> 5) - 8);
  const int tid = threadIdx.x, lane = tid & 63, wid = tid >> 6;   // wid 0..7
  const int qg = wid & 3, ksl = wid >> 2;
  const int l31 = lane & 31, h = lane >> 5;
  const bf16* Qb = Q + (size_t)bh * S_ * D_;
  const bf16* Kb = Kg + (size_t)bh * S_ * D_;
  const bf16* Vb = Vtg + (size_t)bh * D_ * S_;
  const int b = bh >> 4, hd = bh & 15;
  bf16* Ob = Og + (size_t)b * S_ * E_ + hd * D_;

  const int q0 = qblk * 128;
  const int qw0 = q0 + qg * 32;
  const int nkt = 2 * qblk + 2;
  const int nsup = (nkt + 1) >> 1;

  bf16x8 qf[4];
#pragma unroll
  for (int i = 0; i < 4; ++i)
    qf[i] = *reinterpret_cast<const bf16x8*>(Qb + (size_t)(qw0 + l31) * 64 + 16 * i + 8 * h);

  f32x16 oacc0 = {};
  f32x16 oacc1 = {};
  float mrow = -__builtin_inff();
  float lrow = 0.f;
  bool needmax = true;

  auto stagepair = [&](int jp, int dbuf) {
    const int t0 = 2 * jp;
#pragma unroll
    for (int i = 0; i < 2; ++i) {
      const int kc = tid + 512 * i;
      const int tile = kc >> 9, c2 = kc & 511, r = c2 >> 3, cc = c2 & 7;
      gload_lds16(Kb + (size_t)((t0 + tile) * 64 + r) * 64 + ((cc ^ (r & 7)) * 8),
                  &Ks[dbuf][tile][c2 * 8]);
    }
#pragma unroll
    for (int i = 0; i < 2; ++i) {
      const int kc = tid + 512 * i;
      const int tile = kc >> 9, c2 = kc & 511, r = c2 >> 3, cc = c2 & 7;
      gload_lds16(Vb + (size_t)r * S_ + (t0 + tile) * 64 + ((cc ^ (r & 7)) * 8),
                  &Vs[dbuf][tile][c2 * 8]);
    }
  };

  stagepair(0, 0);
  __syncthreads();
  int cur = 0;

  for (int j = 0; j < nsup; ++j) {
    if (j + 1 < nsup) stagepair(j + 1, cur ^ 1);

    const int kt = 2 * j + ksl;
    if (kt < nkt) {
      const int k0 = kt * 64;
      if (k0 <= qw0 + 31) {
        const bf16* ksp = Ks[cur][ksl];
        const bf16* vsp = Vs[cur][ksl];
        f32x16 ps0 = {}, ps1 = {};
        __builtin_amdgcn_s_setprio(1);
#pragma unroll
        for (int i = 0; i < 4; ++i) {
          const bf16x8 ka0 = *reinterpret_cast<const bf16x8*>(
              &ksp[l31 * 64 + (((2 * i + h) ^ (l31 & 7)) * 8)]);
          ps0 = __builtin_amdgcn_mfma_f32_32x32x16_bf16(ka0, qf[i], ps0, 0, 0, 0);
        }
#pragma unroll
        for (int i = 0; i < 4; ++i) {
          const int row1 = 32 + l31;
          const bf16x8 ka1 = *reinterpret_cast<const bf16x8*>(
              &ksp[row1 * 64 + (((2 * i + h) ^ (row1 & 7)) * 8)]);
          ps1 = __builtin_amdgcn_mfma_f32_32x32x16_bf16(ka1, qf[i], ps1, 0, 0, 0);
        }
        __builtin_amdgcn_s_setprio(0);
        if (k0 + 63 > qw0) {
          const int qm = qw0 + l31 - k0;
#pragma unroll
          for (int r = 0; r < 16; ++r) {
            const int kl = (r & 3) + 8 * (r >> 2) + 4 * h;
            if (kl > qm) ps0[r] = -1e30f;
            if (32 + kl > qm) ps1[r] = -1e30f;
          }
        }

        f32x16 p0, p1;
        float ssum;
        if (needmax) {
          float tm = ps0[0];
#pragma unroll
          for (int r = 1; r < 16; ++r) tm = fmaxf(tm, ps0[r]);
#pragma unroll
          for (int r = 0; r < 16; ++r) tm = fmaxf(tm, ps1[r]);
          tm = fmaxf(tm, __shfl_xor(tm, 32));
          mrow = tm;
          needmax = false;
          ssum = 0.f;
#pragma unroll
          for (int r = 0; r < 16; ++r) { p0[r] = exp2f(ps0[r] - mrow); ssum += p0[r]; }
#pragma unroll
          for (int r = 0; r < 16; ++r) { p1[r] = exp2f(ps1[r] - mrow); ssum += p1[r]; }
        } else {
          ssum = 0.f;
#pragma unroll
          for (int r = 0; r < 16; ++r) { p0[r] = exp2f(ps0[r] - mrow); ssum += p0[r]; }
#pragma unroll
          for (int r = 0; r < 16; ++r) { p1[r] = exp2f(ps1[r] - mrow); ssum += p1[r]; }
          if (__any((ssum > 4096.f) ? 1 : 0)) {
            float tm = ps0[0];
#pragma unroll
            for (int r = 1; r < 16; ++r) tm = fmaxf(tm, ps0[r]);
#pragma unroll
            for (int r = 0; r < 16; ++r) tm = fmaxf(tm, ps1[r]);
            tm = fmaxf(tm, __shfl_xor(tm, 32));
            const float mn = fmaxf(mrow, tm);
            const float scl = exp2f(mrow - mn);
            lrow *= scl;
            float so[16];
#pragma unroll
            for (int r = 0; r < 16; ++r)
              so[r] = __shfl(scl, (r & 3) + 8 * (r >> 2) + 4 * h);
#pragma unroll
            for (int r = 0; r < 16; ++r) { oacc0[r] *= so[r]; oacc1[r] *= so[r]; }
            mrow = mn;
            ssum = 0.f;
#pragma unroll
            for (int r = 0; r < 16; ++r) { p0[r] = exp2f(ps0[r] - mrow); ssum += p0[r]; }
#pragma unroll
            for (int r = 0; r < 16; ++r) { p1[r] = exp2f(ps1[r] - mrow); ssum += p1[r]; }
          }
        }
        lrow += ssum;

        unsigned int pk0[8], pk1[8];
#pragma unroll
        for (int i = 0; i < 8; ++i) {
          unsigned int r0, r1;
          asm("v_cvt_pk_bf16_f32 %0, %1, %2" : "=v"(r0) : "v"(p0[2 * i]), "v"(p0[2 * i + 1]));
          asm("v_cvt_pk_bf16_f32 %0, %1, %2" : "=v"(r1) : "v"(p1[2 * i]), "v"(p1[2 * i + 1]));
          pk0[i] = r0; pk1[i] = r1;
        }
#pragma unroll
        for (int ks = 0; ks < 4; ++ks) {
          const int ksq = ks & 1;
          unsigned int w0, w1, w2, w3;
          if (ks < 2) { w0 = pk0[4 * ksq]; w2 = pk0[4 * ksq + 2];
                        w1 = pk0[4 * ksq + 1]; w3 = pk0[4 * ksq + 3]; }
          else        { w0 = pk1[4 * ksq]; w2 = pk1[4 * ksq + 2];
                        w1 = pk1[4 * ksq + 1]; w3 = pk1[4 * ksq + 3]; }
          asm("v_permlane32_swap_b32 %0, %1" : "+v"(w0), "+v"(w2));
          asm("v_permlane32_swap_b32 %0, %1" : "+v"(w1), "+v"(w3));
          union { unsigned int w[4]; bf16x8 v; } Aw;
          Aw.w[0] = w0; Aw.w[1] = w1; Aw.w[2] = w2; Aw.w[3] = w3;
          const int sw = l31 & 7;
          const bf16x8 vf0 = *reinterpret_cast<const bf16x8*>(
              &vsp[l31 * 64 + (((2 * ks + h) ^ sw) * 8)]);
          const bf16x8 vf1 = *reinterpret_cast<const bf16x8*>(
              &vsp[(32 + l31) * 64 + (((2 * ks + h) ^ sw) * 8)]);
          __builtin_amdgcn_s_setprio(1);
          oacc0 = __builtin_amdgcn_mfma_f32_32x32x16_bf16(Aw.v, vf0, oacc0, 0, 0, 0);
          oacc1 = __builtin_amdgcn_mfma_f32_32x32x16_bf16(Aw.v, vf1, oacc1, 0, 0, 0);
          __builtin_amdgcn_s_setprio(0);
        }
      }
    }

    __syncthreads();
    cur ^= 1;
  }

  // combine per-lane partial l across 32-lane halves
  lrow += __shfl_xor(lrow, 32);

  float* Obuf = (float*)&Ks[0][0][0];     // 32 KB: [qg*32+q][64] f32
  float* mlb  = (float*)&Vs[0][0][0];     // 1 KB:  [qg*32+q][2]
  if (ksl == 1) {
#pragma unroll
    for (int r = 0; r < 16; ++r) {
      const int crow = (r & 3) + 8 * (r >> 2) + 4 * h;
      Obuf[(qg * 32 + crow) * 64 + l31] = oacc0[r];
      Obuf[(qg * 32 + crow) * 64 + 32 + l31] = oacc1[r];
    }
    if (h == 0) {
      mlb[(qg * 32 + l31) * 2] = mrow;
      mlb[(qg * 32 + l31) * 2 + 1] = lrow;
    }
  }
  __syncthreads();
  if (ksl == 0) {
    const float pm = mlb[(qg * 32 + l31) * 2];
    const float pl = mlb[(qg * 32 + l31) * 2 + 1];
    const float mstar = fmaxf(mrow, pm);
    const float a = exp2f(mrow - mstar);
    const float bb = exp2f(pm - mstar);
    const float linv = 1.0f / (lrow * a + pl * bb);
    const float fa = a * linv, fb = bb * linv;
#pragma unroll
    for (int r = 0; r < 16; ++r) {
      const int crow = (r & 3) + 8 * (r >> 2) + 4 * h;
      const float far = __shfl(fa, crow);
      const float fbr = __shfl(fb, crow);
      const int qrow = qw0 + crow;
      const float o0 = oacc0[r] * far + Obuf[(qg * 32 + crow) * 64 + l31] * fbr;
      const float o1 = oacc1[r] * far + Obuf[(qg * 32 + crow) * 64 + 32 + l31] * fbr;
      Ob[(size_t)qrow * E_ + l31] = __float2bfloat16(o0);
      Ob[(size_t)qrow * E_ + 32 + l31] = __float2bfloat16(o1);
    }
  }
}

extern "C" void kernel_launch(void* const* d_in, const int* in_sizes, int n_in,
                              void* d_out, int out_size, void* d_ws, size_t ws_size,
                              hipStream_t stream) {
  const float* x  = (const float*)d_in[0];
  const float* Wq = (const float*)d_in[1];
  const float* bq = (const float*)d_in[2];
  const float* Wk = (const float*)d_in[3];
  const float* bk = (const float*)d_in[4];
  const float* Wv = (const float*)d_in[5];
  const float* bv = (const float*)d_in[6];
  const float* Wo = (const float*)d_in[7];
  const float* bo = (const float*)d_in[8];
  float* out = (float*)d_out;

  char* ws = (char*)d_ws;
  size_t off = 0;
  auto alloc = [&](size_t bytes) -> char* {
    char* p = ws + off; off += (bytes + 255) & ~(size_t)255; return p;
  };
  bf16* xb    = (bf16*)alloc((size_t)M_ * E_ * 2);
  bf16* Wqkvb = (bf16*)alloc((size_t)3 * E_ * E_ * 2);
  bf16* Wob   = (bf16*)alloc((size_t)E_ * E_ * 2);
  float* bqkv = (float*)alloc((size_t)3 * E_ * 4);
  bf16* Qb    = (bf16*)alloc((size_t)M_ * E_ * 2);   // [b][h][s][d]
  bf16* Kb    = (bf16*)alloc((size_t)M_ * E_ * 2);   // [b][h][s][d]
  bf16* Vtb   = (bf16*)alloc((size_t)M_ * E_ * 2);   // [b][h][d][s]  (V transposed)
  bf16* AOb   = (bf16*)alloc((size_t)M_ * E_ * 2);   // [b][s][e]
  float* sintab = (float*)alloc((size_t)S_ * 32 * 4);
  float* costab = (float*)alloc((size_t)S_ * 32 * 4);

  prep_kernel<<<dim3(8449), 256, 0, stream>>>(x, Wq, Wk, Wv, Wo, bq, bk, bv,
                                              xb, Wqkvb, Wob, bqkv, sintab, costab);

  gemm_qkv<<<dim3(24, 32), 256, 0, stream>>>(xb, Wqkvb, bqkv, Qb, Kb, Vtb, sintab, costab);
  attn_kernel<<<dim3(512), 512, 0, stream>>>(Qb, Kb, Vtb, AOb);
  gemm_o<<<dim3(512), 256, 0, stream>>>(AOb, Wob, bo, out);
}

// Round 21
// 110.210 us; speedup vs baseline: 1.0969x; 1.0969x over previous
//
#include <hip/hip_runtime.h>
#include <hip/hip_bf16.h>
#include <cstdint>
#include <cstddef>

typedef __hip_bfloat16 bf16;
typedef __attribute__((ext_vector_type(8))) short bf16x8;
typedef __attribute__((ext_vector_type(4))) float f32x4;
typedef __attribute__((ext_vector_type(16))) float f32x16;

#define AS1C(p) ((const __attribute__((address_space(1))) void*)(p))
#define AS3(p)  ((__attribute__((address_space(3))) void*)(p))

constexpr int B_ = 2, S_ = 2048, E_ = 1024, H_ = 16, D_ = 64;
constexpr int M_ = B_ * S_;                      // 4096
constexpr float QSCALE_ = 0.125f * 1.44269504088896340736f;  // 1/sqrt(64) * log2(e)

__device__ __forceinline__ void gload_lds16(const bf16* g, bf16* l) {
  __builtin_amdgcn_global_load_lds(AS1C(g), AS3(l), 16, 0, 0);
}

__device__ __forceinline__ void cast4(const float* __restrict__ in, bf16* __restrict__ out, int i) {
  float4 v = reinterpret_cast<const float4*>(in)[i];
  union { bf16 b[4]; short4 s; } u;
  u.b[0] = __float2bfloat16(v.x);
  u.b[1] = __float2bfloat16(v.y);
  u.b[2] = __float2bfloat16(v.z);
  u.b[3] = __float2bfloat16(v.w);
  reinterpret_cast<short4*>(out)[i] = u.s;
}

// ---------------- fused prep (32B/thread): casts + rope tables + bias concat ----------------
// blocks: [0,2048) x | [2048,2560) Wo | [2560,4096) Wqkv | [4096,4224) rope | 4224 biases
__global__ void prep_kernel(const float* __restrict__ x,
                            const float* __restrict__ Wq, const float* __restrict__ Wk,
                            const float* __restrict__ Wv, const float* __restrict__ Wo,
                            const float* __restrict__ bq, const float* __restrict__ bk,
                            const float* __restrict__ bv,
                            bf16* __restrict__ xb, bf16* __restrict__ Wqkvb,
                            bf16* __restrict__ Wob, float* __restrict__ bqkv,
                            float* __restrict__ sintab, float* __restrict__ costab) {
  const int b = blockIdx.x, t = threadIdx.x;
  if (b < 2048) {
    const int i = (b * 256 + t) * 2;
    cast4(x, xb, i);
    cast4(x, xb, i + 1);
  } else if (b < 2560) {
    const int i = ((b - 2048) * 256 + t) * 2;
    cast4(Wo, Wob, i);
    cast4(Wo, Wob, i + 1);
  } else if (b < 4096) {
    const int i = ((b - 2560) * 256 + t) * 2;      // even; which constant across pair
    const int which = i >> 18;
    const int j = i & ((1 << 18) - 1);
    const float* src = which == 0 ? Wq : (which == 1 ? Wk : Wv);
    bf16* dst = Wqkvb + (size_t)which * E_ * E_;
    cast4(src, dst, j);
    cast4(src, dst, j + 1);
  } else if (b < 4224) {
    const int base = ((b - 4096) * 256 + t) * 2;
#pragma unroll
    for (int u = 0; u < 2; ++u) {
      const int idx = base + u;
      const int s = idx >> 5, i = idx & 31;
      float inv = powf(10000.0f, -(float)i / 32.0f);
      float ang = (float)s * inv;
      sintab[idx] = sinf(ang);
      costab[idx] = cosf(ang);
    }
  } else {
    for (int j = t; j < 768; j += 256) {
      const int which = j >> 8, jj = j & 255;
      const float* src = which == 0 ? bq : (which == 1 ? bk : bv);
      reinterpret_cast<float4*>(bqkv)[j] = reinterpret_cast<const float4*>(src)[jj];
    }
  }
}

// ---------------- QKV GEMM: 128x128, chunk-XOR swizzle, 2-phase double-buffered K-loop ----------------
__global__ __launch_bounds__(256)
void gemm_qkv(const bf16* __restrict__ A, const bf16* __restrict__ W,
              const float* __restrict__ bias,
              bf16* __restrict__ Qo, bf16* __restrict__ Ko, bf16* __restrict__ Vo,
              const float* __restrict__ sintab, const float* __restrict__ costab)
{
  constexpr int K = 1024, BK = 32;
  __shared__ __align__(16) bf16 smem[17408];
  const int tid = threadIdx.x;
  const int lane = tid & 63, wid = tid >> 6;
  const int g = lane >> 4, r16 = lane & 15;
  const int wr = wid >> 1, wc = wid & 1;
  const int swzr = (r16 >> 1) & 3;

  const int nwg = gridDim.x * gridDim.y;
  const int flat = blockIdx.y * gridDim.x + blockIdx.x;
  const int cpx = nwg >> 3;
  const int f2 = (flat & 7) * cpx + (flat >> 3);
  const int m0 = (f2 / gridDim.x) * 128, n0 = (f2 % gridDim.x) * 128;

  const f32x4 fz = {0.f, 0.f, 0.f, 0.f};
  f32x4 acc[4][4];
#pragma unroll
  for (int mi = 0; mi < 4; ++mi)
#pragma unroll
    for (int ni = 0; ni < 4; ++ni) acc[mi][ni] = fz;

  const bf16* Abase = A + (size_t)m0 * K;
  const bf16* Wbase = W + (size_t)n0 * K;
  const int c0 = tid, c1 = 256 + tid;
  const int r0c = c0 >> 2, cc0 = c0 & 3, sw0 = (r0c >> 1) & 3;
  const int r1c = c1 >> 2, cc1 = c1 & 3, sw1 = (r1c >> 1) & 3;

  auto stage = [&](int k0, int buf) {
    bf16* As = smem + buf * 4096;
    bf16* Bs = smem + 8192 + buf * 4096;
    gload_lds16(Abase + (size_t)r0c * K + k0 + ((cc0 ^ sw0) * 8), As + c0 * 8);
    gload_lds16(Abase + (size_t)r1c * K + k0 + ((cc1 ^ sw1) * 8), As + c1 * 8);
    gload_lds16(Wbase + (size_t)r0c * K + k0 + ((cc0 ^ sw0) * 8), Bs + c0 * 8);
    gload_lds16(Wbase + (size_t)r1c * K + k0 + ((cc1 ^ sw1) * 8), Bs + c1 * 8);
  };

  stage(0, 0);
  __syncthreads();
  int buf = 0;

  for (int k0 = 0; k0 < K; k0 += BK) {
    if (k0 + BK < K) stage(k0 + BK, buf ^ 1);

    const bf16* As = smem + buf * 4096;
    const bf16* Bs = smem + 8192 + buf * 4096;
    bf16x8 af[4], bfr[4];
#pragma unroll
    for (int mi = 0; mi < 4; ++mi)
      af[mi] = *reinterpret_cast<const bf16x8*>(
          As + (wr * 64 + mi * 16 + r16) * BK + 8 * (g ^ swzr));
#pragma unroll
    for (int ni = 0; ni < 4; ++ni)
      bfr[ni] = *reinterpret_cast<const bf16x8*>(
          Bs + (wc * 64 + ni * 16 + r16) * BK + 8 * (g ^ swzr));
    __builtin_amdgcn_s_setprio(1);
#pragma unroll
    for (int mi = 0; mi < 4; ++mi)
#pragma unroll
      for (int ni = 0; ni < 4; ++ni)
        acc[mi][ni] = __builtin_amdgcn_mfma_f32_16x16x32_bf16(af[mi], bfr[ni], acc[mi][ni], 0, 0, 0);
    __builtin_amdgcn_s_setprio(0);

    __syncthreads();
    buf ^= 1;
  }

  const int b = m0 >> 11;
  if (n0 >= 2048) {
#pragma unroll
    for (int mi = 0; mi < 4; ++mi) {
#pragma unroll
      for (int ni = 0; ni < 4; ++ni) {
        const int n_local = wc * 64 + ni * 16 + r16;
        const float bv = bias[n0 + n_local];
        const int m_base = wr * 64 + mi * 16 + g * 4;
        union { bf16 b4[4]; short4 s4; } u;
#pragma unroll
        for (int r = 0; r < 4; ++r) u.b4[r] = __float2bfloat16(acc[mi][ni][r] + bv);
        *reinterpret_cast<short4*>(&smem[n_local * 136 + m_base]) = u.s4;
      }
    }
    __syncthreads();
    const int srow0 = m0 & (S_ - 1);
#pragma unroll
    for (int i = 0; i < 8; ++i) {
      const int c = i * 256 + tid;
      const int row = c >> 4, cc = c & 15;
      const bf16x8 v = *reinterpret_cast<const bf16x8*>(&smem[row * 136 + cc * 8]);
      const int n = n0 + row;
      const int h = (n >> 6) & 15, d = n & 63;
      *reinterpret_cast<bf16x8*>(&Vo[((size_t)(b * H_ + h) * D_ + d) * S_ + srow0 + cc * 8]) = v;
    }
  } else {
#pragma unroll
    for (int mi = 0; mi < 4; ++mi) {
#pragma unroll
      for (int ni = 0; ni < 4; ++ni) {
        const int gn = n0 + wc * 64 + ni * 16 + r16;
        const float bv = bias[gn];
#pragma unroll
        for (int r = 0; r < 4; ++r) {
          const int gm = m0 + wr * 64 + mi * 16 + g * 4 + r;
          float val = acc[mi][ni][r] + bv;
          const int d = gn & 63;
          const int srow = gm & (S_ - 1);
          const float cs = costab[srow * 32 + (d >> 1)];
          const float sn = sintab[srow * 32 + (d >> 1)];
          const float pv = __shfl_xor(val, 1);
          val = (d & 1) ? (val * cs + pv * sn) : (val * cs - pv * sn);
          const int h = (gn >> 6) & 15;
          const size_t bh = (size_t)(b * H_ + h);
          if (gn < 1024) {
            Qo[(bh * S_ + srow) * D_ + d] = __float2bfloat16(val * QSCALE_);
          } else {
            Ko[(bh * S_ + srow) * D_ + d] = __float2bfloat16(val);
          }
        }
      }
    }
  }
}

// ---------------- O-projection GEMM: BM=64 x BN=128, swizzle + 2-phase dbuf ----------------
__global__ __launch_bounds__(256)
void gemm_o(const bf16* __restrict__ A, const bf16* __restrict__ W,
            const float* __restrict__ bias, float* __restrict__ outF)
{
  constexpr int K = 1024, BK = 32;
  __shared__ __align__(16) bf16 As[2][64 * BK];
  __shared__ __align__(16) bf16 Bs[2][128 * BK];
  const int tid = threadIdx.x;
  const int lane = tid & 63;
  const int wc = tid >> 6;
  const int g = lane >> 4, r16 = lane & 15;
  const int swzr = (r16 >> 1) & 3;

  const int flat = blockIdx.x;                    // 512
  const int f2 = (flat & 7) * 64 + (flat >> 3);
  const int m0 = (f2 >> 3) * 64, n0 = (f2 & 7) * 128;

  const f32x4 fz = {0.f, 0.f, 0.f, 0.f};
  f32x4 acc[4][2];
#pragma unroll
  for (int mi = 0; mi < 4; ++mi)
#pragma unroll
    for (int ni = 0; ni < 2; ++ni) acc[mi][ni] = fz;

  const bf16* Abase = A + (size_t)m0 * K;
  const bf16* Wbase = W + (size_t)n0 * K;
  const int c0 = tid, c1 = 256 + tid;
  const int r0c = c0 >> 2, cc0 = c0 & 3, sw0 = (r0c >> 1) & 3;
  const int r1c = c1 >> 2, cc1 = c1 & 3, sw1 = (r1c >> 1) & 3;

  auto stage = [&](int k0, int buf) {
    gload_lds16(Abase + (size_t)r0c * K + k0 + ((cc0 ^ sw0) * 8), As[buf] + c0 * 8);
    gload_lds16(Wbase + (size_t)r0c * K + k0 + ((cc0 ^ sw0) * 8), Bs[buf] + c0 * 8);
    gload_lds16(Wbase + (size_t)r1c * K + k0 + ((cc1 ^ sw1) * 8), Bs[buf] + c1 * 8);
  };

  stage(0, 0);
  __syncthreads();
  int buf = 0;

  for (int k0 = 0; k0 < K; k0 += BK) {
    if (k0 + BK < K) stage(k0 + BK, buf ^ 1);

    bf16x8 af[4], bfr[2];
#pragma unroll
    for (int mi = 0; mi < 4; ++mi)
      af[mi] = *reinterpret_cast<const bf16x8*>(
          As[buf] + (mi * 16 + r16) * BK + 8 * (g ^ swzr));
#pragma unroll
    for (int ni = 0; ni < 2; ++ni)
      bfr[ni] = *reinterpret_cast<const bf16x8*>(
          Bs[buf] + (wc * 32 + ni * 16 + r16) * BK + 8 * (g ^ swzr));
    __builtin_amdgcn_s_setprio(1);
#pragma unroll
    for (int mi = 0; mi < 4; ++mi)
#pragma unroll
      for (int ni = 0; ni < 2; ++ni)
        acc[mi][ni] = __builtin_amdgcn_mfma_f32_16x16x32_bf16(af[mi], bfr[ni], acc[mi][ni], 0, 0, 0);
    __builtin_amdgcn_s_setprio(0);

    __syncthreads();
    buf ^= 1;
  }

#pragma unroll
  for (int mi = 0; mi < 4; ++mi)
#pragma unroll
    for (int ni = 0; ni < 2; ++ni) {
      const int gn = n0 + wc * 32 + ni * 16 + r16;
      const float bv = bias[gn];
#pragma unroll
      for (int r = 0; r < 4; ++r) {
        const int gm = m0 + mi * 16 + g * 4 + r;
        outF[(size_t)gm * 1024 + gn] = acc[mi][ni][r] + bv;
      }
    }
}

// ---------------- causal flash attention v12 (round-19 best): heavy-first, lazy softmax ----------------
__global__ __launch_bounds__(512)
void attn_kernel(const bf16* __restrict__ Q, const bf16* __restrict__ Kg,
                 const bf16* __restrict__ Vtg, bf16* __restrict__ Og)
{
  __shared__ __align__(16) bf16 Ks[2][2][64 * 64];   // [dbuf][tile-in-pair][k][d]
  __shared__ __align__(16) bf16 Vs[2][2][64 * 64];   // [dbuf][tile-in-pair][d][k]
  const int flat = blockIdx.x;
  const int bh = flat & 31;
  const int qblk = 15 - (flat >> 5);              // heavy-first
  const int tid = threadIdx.x, lane = tid & 63, wid = tid >> 6;   // wid 0..7
  const int qg = wid & 3, ksl = wid >> 2;
  const int l31 = lane & 31, h = lane >> 5;
  const bf16* Qb = Q + (size_t)bh * S_ * D_;
  const bf16* Kb = Kg + (size_t)bh * S_ * D_;
  const bf16* Vb = Vtg + (size_t)bh * D_ * S_;
  const int b = bh >> 4, hd = bh & 15;
  bf16* Ob = Og + (size_t)b * S_ * E_ + hd * D_;

  const int q0 = qblk * 128;
  const int qw0 = q0 + qg * 32;
  const int nkt = 2 * qblk + 2;
  const int nsup = (nkt + 1) >> 1;

  bf16x8 qf[4];
#pragma unroll
  for (int i = 0; i < 4; ++i)
    qf[i] = *reinterpret_cast<const bf16x8*>(Qb + (size_t)(qw0 + l31) * 64 + 16 * i + 8 * h);

  f32x16 oacc0 = {};
  f32x16 oacc1 = {};
  float mrow = -__builtin_inff();
  float lrow = 0.f;
  bool needmax = true;

  auto stagepair = [&](int jp, int dbuf) {
    const int t0 = 2 * jp;
#pragma unroll
    for (int i = 0; i < 2; ++i) {
      const int kc = tid + 512 * i;
      const int tile = kc >> 9, c2 = kc & 511, r = c2 >> 3, cc = c2 & 7;
      gload_lds16(Kb + (size_t)((t0 + tile) * 64 + r) * 64 + ((cc ^ (r & 7)) * 8),
                  &Ks[dbuf][tile][c2 * 8]);
    }
#pragma unroll
    for (int i = 0; i < 2; ++i) {
      const int kc = tid + 512 * i;
      const int tile = kc >> 9, c2 = kc & 511, r = c2 >> 3, cc = c2 & 7;
      gload_lds16(Vb + (size_t)r * S_ + (t0 + tile) * 64 + ((cc ^ (r & 7)) * 8),
                  &Vs[dbuf][tile][c2 * 8]);
    }
  };

  stagepair(0, 0);
  __syncthreads();
  int cur = 0;

  for (int j = 0; j < nsup; ++j) {
    if (j + 1 < nsup) stagepair(j + 1, cur ^ 1);

    const int kt = 2 * j + ksl;
    if (kt < nkt) {
      const int k0 = kt * 64;
      if (k0 <= qw0 + 31) {
        const bf16* ksp = Ks[cur][ksl];
        const bf16* vsp = Vs[cur][ksl];
        f32x16 ps0 = {}, ps1 = {};
        __builtin_amdgcn_s_setprio(1);
#pragma unroll
        for (int i = 0; i < 4; ++i) {
          const bf16x8 ka0 = *reinterpret_cast<const bf16x8*>(
              &ksp[l31 * 64 + (((2 * i + h) ^ (l31 & 7)) * 8)]);
          ps0 = __builtin_amdgcn_mfma_f32_32x32x16_bf16(ka0, qf[i], ps0, 0, 0, 0);
        }
#pragma unroll
        for (int i = 0; i < 4; ++i) {
          const int row1 = 32 + l31;
          const bf16x8 ka1 = *reinterpret_cast<const bf16x8*>(
              &ksp[row1 * 64 + (((2 * i + h) ^ (row1 & 7)) * 8)]);
          ps1 = __builtin_amdgcn_mfma_f32_32x32x16_bf16(ka1, qf[i], ps1, 0, 0, 0);
        }
        __builtin_amdgcn_s_setprio(0);
        if (k0 + 63 > qw0) {
          const int qm = qw0 + l31 - k0;
#pragma unroll
          for (int r = 0; r < 16; ++r) {
            const int kl = (r & 3) + 8 * (r >> 2) + 4 * h;
            if (kl > qm) ps0[r] = -1e30f;
            if (32 + kl > qm) ps1[r] = -1e30f;
          }
        }

        f32x16 p0, p1;
        float ssum;
        if (needmax) {
          float tm = ps0[0];
#pragma unroll
          for (int r = 1; r < 16; ++r) tm = fmaxf(tm, ps0[r]);
#pragma unroll
          for (int r = 0; r < 16; ++r) tm = fmaxf(tm, ps1[r]);
          tm = fmaxf(tm, __shfl_xor(tm, 32));
          mrow = tm;
          needmax = false;
          ssum = 0.f;
#pragma unroll
          for (int r = 0; r < 16; ++r) { p0[r] = exp2f(ps0[r] - mrow); ssum += p0[r]; }
#pragma unroll
          for (int r = 0; r < 16; ++r) { p1[r] = exp2f(ps1[r] - mrow); ssum += p1[r]; }
        } else {
          ssum = 0.f;
#pragma unroll
          for (int r = 0; r < 16; ++r) { p0[r] = exp2f(ps0[r] - mrow); ssum += p0[r]; }
#pragma unroll
          for (int r = 0; r < 16; ++r) { p1[r] = exp2f(ps1[r] - mrow); ssum += p1[r]; }
          if (__any((ssum > 4096.f) ? 1 : 0)) {
            float tm = ps0[0];
#pragma unroll
            for (int r = 1; r < 16; ++r) tm = fmaxf(tm, ps0[r]);
#pragma unroll
            for (int r = 0; r < 16; ++r) tm = fmaxf(tm, ps1[r]);
            tm = fmaxf(tm, __shfl_xor(tm, 32));
            const float mn = fmaxf(mrow, tm);
            const float scl = exp2f(mrow - mn);
            lrow *= scl;
            float so[16];
#pragma unroll
            for (int r = 0; r < 16; ++r)
              so[r] = __shfl(scl, (r & 3) + 8 * (r >> 2) + 4 * h);
#pragma unroll
            for (int r = 0; r < 16; ++r) { oacc0[r] *= so[r]; oacc1[r] *= so[r]; }
            mrow = mn;
            ssum = 0.f;
#pragma unroll
            for (int r = 0; r < 16; ++r) { p0[r] = exp2f(ps0[r] - mrow); ssum += p0[r]; }
#pragma unroll
            for (int r = 0; r < 16; ++r) { p1[r] = exp2f(ps1[r] - mrow); ssum += p1[r]; }
          }
        }
        lrow += ssum;

        unsigned int pk0[8], pk1[8];
#pragma unroll
        for (int i = 0; i < 8; ++i) {
          unsigned int r0, r1;
          asm("v_cvt_pk_bf16_f32 %0, %1, %2" : "=v"(r0) : "v"(p0[2 * i]), "v"(p0[2 * i + 1]));
          asm("v_cvt_pk_bf16_f32 %0, %1, %2" : "=v"(r1) : "v"(p1[2 * i]), "v"(p1[2 * i + 1]));
          pk0[i] = r0; pk1[i] = r1;
        }
#pragma unroll
        for (int ks = 0; ks < 4; ++ks) {
          const int ksq = ks & 1;
          unsigned int w0, w1, w2, w3;
          if (ks < 2) { w0 = pk0[4 * ksq]; w2 = pk0[4 * ksq + 2];
                        w1 = pk0[4 * ksq + 1]; w3 = pk0[4 * ksq + 3]; }
          else        { w0 = pk1[4 * ksq]; w2 = pk1[4 * ksq + 2];
                        w1 = pk1[4 * ksq + 1]; w3 = pk1[4 * ksq + 3]; }
          asm("v_permlane32_swap_b32 %0, %1" : "+v"(w0), "+v"(w2));
          asm("v_permlane32_swap_b32 %0, %1" : "+v"(w1), "+v"(w3));
          union { unsigned int w[4]; bf16x8 v; } Aw;
          Aw.w[0] = w0; Aw.w[1] = w1; Aw.w[2] = w2; Aw.w[3] = w3;
          const int sw = l31 & 7;
          const bf16x8 vf0 = *reinterpret_cast<const bf16x8*>(
              &vsp[l31 * 64 + (((2 * ks + h) ^ sw) * 8)]);
          const bf16x8 vf1 = *reinterpret_cast<const bf16x8*>(
              &vsp[(32 + l31) * 64 + (((2 * ks + h) ^ sw) * 8)]);
          __builtin_amdgcn_s_setprio(1);
          oacc0 = __builtin_amdgcn_mfma_f32_32x32x16_bf16(Aw.v, vf0, oacc0, 0, 0, 0);
          oacc1 = __builtin_amdgcn_mfma_f32_32x32x16_bf16(Aw.v, vf1, oacc1, 0, 0, 0);
          __builtin_amdgcn_s_setprio(0);
        }
      }
    }

    __syncthreads();
    cur ^= 1;
  }

  // combine per-lane partial l across 32-lane halves
  lrow += __shfl_xor(lrow, 32);

  float* Obuf = (float*)&Ks[0][0][0];     // 32 KB: [qg*32+q][64] f32
  float* mlb  = (float*)&Vs[0][0][0];     // 1 KB:  [qg*32+q][2]
  if (ksl == 1) {
#pragma unroll
    for (int r = 0; r < 16; ++r) {
      const int crow = (r & 3) + 8 * (r >> 2) + 4 * h;
      Obuf[(qg * 32 + crow) * 64 + l31] = oacc0[r];
      Obuf[(qg * 32 + crow) * 64 + 32 + l31] = oacc1[r];
    }
    if (h == 0) {
      mlb[(qg * 32 + l31) * 2] = mrow;
      mlb[(qg * 32 + l31) * 2 + 1] = lrow;
    }
  }
  __syncthreads();
  if (ksl == 0) {
    const float pm = mlb[(qg * 32 + l31) * 2];
    const float pl = mlb[(qg * 32 + l31) * 2 + 1];
    const float mstar = fmaxf(mrow, pm);
    const float a = exp2f(mrow - mstar);
    const float bb = exp2f(pm - mstar);
    const float linv = 1.0f / (lrow * a + pl * bb);
    const float fa = a * linv, fb = bb * linv;
#pragma unroll
    for (int r = 0; r < 16; ++r) {
      const int crow = (r & 3) + 8 * (r >> 2) + 4 * h;
      const float far = __shfl(fa, crow);
      const float fbr = __shfl(fb, crow);
      const int qrow = qw0 + crow;
      const float o0 = oacc0[r] * far + Obuf[(qg * 32 + crow) * 64 + l31] * fbr;
      const float o1 = oacc1[r] * far + Obuf[(qg * 32 + crow) * 64 + 32 + l31] * fbr;
      Ob[(size_t)qrow * E_ + l31] = __float2bfloat16(o0);
      Ob[(size_t)qrow * E_ + 32 + l31] = __float2bfloat16(o1);
    }
  }
}

extern "C" void kernel_launch(void* const* d_in, const int* in_sizes, int n_in,
                              void* d_out, int out_size, void* d_ws, size_t ws_size,
                              hipStream_t stream) {
  const float* x  = (const float*)d_in[0];
  const float* Wq = (const float*)d_in[1];
  const float* bq = (const float*)d_in[2];
  const float* Wk = (const float*)d_in[3];
  const float* bk = (const float*)d_in[4];
  const float* Wv = (const float*)d_in[5];
  const float* bv = (const float*)d_in[6];
  const float* Wo = (const float*)d_in[7];
  const float* bo = (const float*)d_in[8];
  float* out = (float*)d_out;

  char* ws = (char*)d_ws;
  size_t off = 0;
  auto alloc = [&](size_t bytes) -> char* {
    char* p = ws + off; off += (bytes + 255) & ~(size_t)255; return p;
  };
  bf16* xb    = (bf16*)alloc((size_t)M_ * E_ * 2);
  bf16* Wqkvb = (bf16*)alloc((size_t)3 * E_ * E_ * 2);
  bf16* Wob   = (bf16*)alloc((size_t)E_ * E_ * 2);
  float* bqkv = (float*)alloc((size_t)3 * E_ * 4);
  bf16* Qb    = (bf16*)alloc((size_t)M_ * E_ * 2);   // [b][h][s][d]
  bf16* Kb    = (bf16*)alloc((size_t)M_ * E_ * 2);   // [b][h][s][d]
  bf16* Vtb   = (bf16*)alloc((size_t)M_ * E_ * 2);   // [b][h][d][s]  (V transposed)
  bf16* AOb   = (bf16*)alloc((size_t)M_ * E_ * 2);   // [b][s][e]
  float* sintab = (float*)alloc((size_t)S_ * 32 * 4);
  float* costab = (float*)alloc((size_t)S_ * 32 * 4);

  prep_kernel<<<dim3(4225), 256, 0, stream>>>(x, Wq, Wk, Wv, Wo, bq, bk, bv,
                                              xb, Wqkvb, Wob, bqkv, sintab, costab);

  gemm_qkv<<<dim3(24, 32), 256, 0, stream>>>(xb, Wqkvb, bqkv, Qb, Kb, Vtb, sintab, costab);
  attn_kernel<<<dim3(512), 512, 0, stream>>>(Qb, Kb, Vtb, AOb);
  gemm_o<<<dim3(512), 256, 0, stream>>>(AOb, Wob, bo, out);
}